// Round 15
// baseline (65.078 us; speedup 1.0000x reference)
//
#include <hip/hip_runtime.h>
#include <hip/hip_bf16.h>

// RBF kernel matrix: out[i][j] = exp(-gamma * max(x2[i] + y2[j] - 2*x.y, 0))
//
// Round 15: r14 discipline generalized to a 4-tile strip (JT=4).
// Per block: stage X+Y0 once, then per tile t: hoist B(t) frags ->
// lgkmcnt(0)+raw s_barrier (Y region free; does NOT drain stores) ->
// issue Y(t+1) DMA -> 16 fenced sub-tiles (6 MFMA + 4 exp + 1 store,
// sched_barrier(0) pinned) -> vmcnt(16)+raw s_barrier (waits the 8 DMA
// loads = oldest ops; the 16 younger stores stay in flight). One store-less
// prologue per 256 KB of output (~5% idle, was ~10% at JT=2).
// 3 MFMA passes (hh + loY*hiX + hiY*loX), drop lo*lo (~1e-21 abs err).

#define DD 64
#define BM 128
#define BN 128
#define JT 4

typedef __attribute__((ext_vector_type(8))) short short8;
typedef __attribute__((ext_vector_type(4))) float f32x4;

#if __has_builtin(__builtin_amdgcn_exp2f)
#define EXP2(x) __builtin_amdgcn_exp2f(x)
#else
#define EXP2(x) exp2f(x)
#endif

__device__ __forceinline__ unsigned short f2bf_rne(float f) {
  unsigned u = __float_as_uint(f);
  unsigned r = u + 0x7FFFu + ((u >> 16) & 1u);
  return (unsigned short)(r >> 16);
}

// ---------------- prep: fp32 norms + bf16 hi/lo pre-split (pre-swizzled) ----
__global__ __launch_bounds__(256)
void prep_split(const float* __restrict__ X, const float* __restrict__ Y,
                unsigned short* __restrict__ XHg, unsigned short* __restrict__ XLg,
                unsigned short* __restrict__ YHg, unsigned short* __restrict__ YLg,
                float* __restrict__ xsq, float* __restrict__ ysq, int n) {
  int t = blockIdx.x * 256 + threadIdx.x;
  int row = t >> 4;       // 16 lanes per row
  int c4 = t & 15;        // float4 index within row
  const float* src;
  unsigned short *hd, *ld;
  float* nd;
  int r;
  if (row < n) { r = row;     src = X + (long)r * DD; hd = XHg; ld = XLg; nd = xsq + r; }
  else         { r = row - n; src = Y + (long)r * DD; hd = YHg; ld = YLg; nd = ysq + r; }
  float4 v = ((const float4*)src)[c4];
  float f[4] = {v.x, v.y, v.z, v.w};
  unsigned short h[4], l[4];
#pragma unroll
  for (int q = 0; q < 4; ++q) {
    h[q] = f2bf_rne(f[q]);
    float hv = __uint_as_float(((unsigned)h[q]) << 16);
    l[q] = f2bf_rne(f[q] - hv);
  }
  int sw = (c4 * 8) ^ ((r & 7) << 4);   // swizzled byte offset within 128-B row
  *(ushort4*)((char*)hd + (long)r * 128 + sw) = make_ushort4(h[0], h[1], h[2], h[3]);
  *(ushort4*)((char*)ld + (long)r * 128 + sw) = make_ushort4(l[0], l[1], l[2], l[3]);
  float s = v.x * v.x + v.y * v.y + v.z * v.z + v.w * v.w;
  s += __shfl_xor(s, 1);
  s += __shfl_xor(s, 2);
  s += __shfl_xor(s, 4);
  s += __shfl_xor(s, 8);
  if (c4 == 0) *nd = s;
}

// ---------------- main: 4-tile pipelined strip, fenced sub-tile stores ------
__global__ __launch_bounds__(256, 2)
void rbf_4t(const unsigned short* __restrict__ XHg, const unsigned short* __restrict__ XLg,
            const unsigned short* __restrict__ YHg, const unsigned short* __restrict__ YLg,
            const float* __restrict__ gptr,
            const float* __restrict__ xsq, const float* __restrict__ ysq,
            float* __restrict__ Out, int mcols) {
  // [0,16K) XH  [16K,32K) XL  [32K,48K) YH(cur)  [48K,64K) YL(cur)
  __shared__ __align__(128) char lds[65536];

  const int tid = threadIdx.x;
  const int lane = tid & 63;
  const int wid = tid >> 6;        // 0..3
  const long i0 = (long)blockIdx.y * BM;
  const long j0base = (long)blockIdx.x * (JT * BN);   // 512-col strip

  // ---- prologue stage: XH, XL, YH(t0), YL(t0) — 16 KB each
  const char* srcs[4] = {(const char*)XHg + i0 * 128, (const char*)XLg + i0 * 128,
                         (const char*)YHg + j0base * 128, (const char*)YLg + j0base * 128};
#pragma unroll
  for (int t4 = 0; t4 < 4; ++t4) {
#pragma unroll
    for (int it = 0; it < 4; ++it) {
      int off = it * 4096 + wid * 1024;           // wave-uniform
      const char* gp = srcs[t4] + off + lane * 16;
      __builtin_amdgcn_global_load_lds(
          (const __attribute__((address_space(1))) void*)gp,
          (__attribute__((address_space(3))) void*)(lds + t4 * 16384 + off),
          16, 0, 0);
    }
  }
  __syncthreads();   // drain prologue DMA (no stores outstanding yet)

  const int wr = wid >> 1, wc = wid & 1;
  const int lr = lane & 15;
  const int hg = lane >> 4;        // 0..3

  // ---- hoist A frags (persist across all tiles)
  short8 afh[2][4], afl[2][4];     // [s][m2]
#pragma unroll
  for (int s = 0; s < 2; ++s)
#pragma unroll
    for (int q = 0; q < 4; ++q) {
      int ra = wr * 64 + q * 16 + lr;
      int oa = (s * 64 + hg * 16) ^ ((ra & 7) << 4);
      afh[s][q] = *(const short8*)(lds + ra * 128 + oa);
      afl[s][q] = *(const short8*)(lds + 16384 + ra * 128 + oa);
    }

  const float g = *gptr;
  const float cf = -g * 1.4426950408889634f;   // -gamma*log2(e)
  const float nc2 = -2.0f * cf;
  float cxr[4];
#pragma unroll
  for (int m2 = 0; m2 < 4; ++m2) cxr[m2] = cf * xsq[i0 + wr * 64 + m2 * 16 + lr];

  for (int t = 0; t < JT; ++t) {
    const long j0 = j0base + (long)t * BN;

    // ---- hoist B(t) frags from the Y LDS region
    short8 bfh[2][4], bfl[2][4];   // [s][n2]
#pragma unroll
    for (int s = 0; s < 2; ++s)
#pragma unroll
      for (int q = 0; q < 4; ++q) {
        int rb = wc * 64 + q * 16 + lr;
        int ob = (s * 64 + hg * 16) ^ ((rb & 7) << 4);
        bfh[s][q] = *(const short8*)(lds + 32768 + rb * 128 + ob);
        bfl[s][q] = *(const short8*)(lds + 49152 + rb * 128 + ob);
      }

    if (t + 1 < JT) {
      // Y region free once all waves' ds_reads retired; raw barrier keeps
      // older stores in flight (no vmcnt drain).
      asm volatile("s_waitcnt lgkmcnt(0)" ::: "memory");
      __builtin_amdgcn_s_barrier();
      // issue Y(t+1) DMA into the same Y LDS region
      const char* yh = (const char*)YHg + (j0 + BN) * 128;
      const char* yl = (const char*)YLg + (j0 + BN) * 128;
#pragma unroll
      for (int it = 0; it < 4; ++it) {
        int off = it * 4096 + wid * 1024;
        __builtin_amdgcn_global_load_lds(
            (const __attribute__((address_space(1))) void*)(yh + off + lane * 16),
            (__attribute__((address_space(3))) void*)(lds + 32768 + off), 16, 0, 0);
        __builtin_amdgcn_global_load_lds(
            (const __attribute__((address_space(1))) void*)(yl + off + lane * 16),
            (__attribute__((address_space(3))) void*)(lds + 49152 + off), 16, 0, 0);
      }
    }

    // ---- 16 fenced sub-tiles: 6 MFMAs + 4 exp + 1 float4 store each
    float4 cyv[4];
#pragma unroll
    for (int n2 = 0; n2 < 4; ++n2) {
      float4 yq = *(const float4*)&ysq[j0 + wc * 64 + n2 * 16 + hg * 4];
      cyv[n2] = make_float4(cf * yq.x, cf * yq.y, cf * yq.z, cf * yq.w);
    }
#pragma unroll
    for (int m2 = 0; m2 < 4; ++m2) {
      long row = i0 + wr * 64 + m2 * 16 + lr;
      float* op = Out + row * (long)mcols + j0 + wc * 64 + hg * 4;
#pragma unroll
      for (int n2 = 0; n2 < 4; ++n2) {
        f32x4 a = (f32x4){0.f, 0.f, 0.f, 0.f};
#pragma unroll
        for (int s = 0; s < 2; ++s) {
          a = __builtin_amdgcn_mfma_f32_16x16x32_bf16(bfh[s][n2], afh[s][m2], a, 0, 0, 0);
          a = __builtin_amdgcn_mfma_f32_16x16x32_bf16(bfh[s][n2], afl[s][m2], a, 0, 0, 0);
          a = __builtin_amdgcn_mfma_f32_16x16x32_bf16(bfl[s][n2], afh[s][m2], a, 0, 0, 0);
        }
        float o[4];
        o[0] = EXP2(fminf(fmaf(nc2, a[0], cxr[m2] + cyv[n2].x), 0.f));
        o[1] = EXP2(fminf(fmaf(nc2, a[1], cxr[m2] + cyv[n2].y), 0.f));
        o[2] = EXP2(fminf(fmaf(nc2, a[2], cxr[m2] + cyv[n2].z), 0.f));
        o[3] = EXP2(fminf(fmaf(nc2, a[3], cxr[m2] + cyv[n2].w), 0.f));
        *(float4*)(op + n2 * 16) = *(float4*)o;
        __builtin_amdgcn_sched_barrier(0);   // pin store spacing
      }
    }

    if (t + 1 < JT) {
      // wait ONLY the 8 DMA loads (oldest); the 16 newest ops (this tile's
      // stores) stay in flight. Then converge so all waves' DMA landed.
      asm volatile("s_waitcnt vmcnt(16)" ::: "memory");
      __builtin_amdgcn_s_barrier();
    }
  }
}

// ---------------- fallback (proven round-2 path) ---------------------------
__global__ __launch_bounds__(256)
void prep_sq(const float* __restrict__ X, const float* __restrict__ Y,
             float* __restrict__ xsq, float* __restrict__ ysq, int n) {
  int t = blockIdx.x * 256 + threadIdx.x;
  int row = t >> 4;
  int c = t & 15;
  const float* src;
  float* dst;
  if (row < n) { src = X + (long)row * DD; dst = xsq + row; }
  else         { src = Y + (long)(row - n) * DD; dst = ysq + (row - n); }
  float4 v = ((const float4*)src)[c];
  float s = v.x * v.x + v.y * v.y + v.z * v.z + v.w * v.w;
  s += __shfl_xor(s, 1);
  s += __shfl_xor(s, 2);
  s += __shfl_xor(s, 4);
  s += __shfl_xor(s, 8);
  if (c == 0) *dst = s;
}

__global__ __launch_bounds__(256, 2)
void rbf_mfma_fb(const float* __restrict__ X, const float* __restrict__ Y,
                 const float* __restrict__ gptr,
                 const float* __restrict__ xsq, const float* __restrict__ ysq,
                 float* __restrict__ Out, int mcols) {
  __shared__ unsigned short XH[128 * DD], XL[128 * DD];
  __shared__ unsigned short YH[128 * DD], YL[128 * DD];
  const int tid = threadIdx.x;
  const long i0 = (long)blockIdx.y * 128;
  const long j0 = (long)blockIdx.x * 128;
#pragma unroll
  for (int it = 0; it < 16; ++it) {
    int e = it * 256 + tid;
    int half = e >> 11;
    int idx = e & 2047;
    int row = idx >> 4;
    int c4 = idx & 15;
    const float* src = half ? (Y + (j0 + row) * DD) : (X + (i0 + row) * DD);
    float4 v = ((const float4*)src)[c4];
    float f[4] = {v.x, v.y, v.z, v.w};
    unsigned short h[4], l[4];
#pragma unroll
    for (int q = 0; q < 4; ++q) {
      h[q] = f2bf_rne(f[q]);
      float hv = __uint_as_float(((unsigned)h[q]) << 16);
      l[q] = f2bf_rne(f[q] - hv);
    }
    int sw = (c4 * 8) ^ ((row & 7) << 4);
    unsigned short* Ht = half ? YH : XH;
    unsigned short* Lt = half ? YL : XL;
    *(ushort4*)((char*)Ht + row * 128 + sw) = make_ushort4(h[0], h[1], h[2], h[3]);
    *(ushort4*)((char*)Lt + row * 128 + sw) = make_ushort4(l[0], l[1], l[2], l[3]);
  }
  __syncthreads();
  const int lane = tid & 63;
  const int wid = tid >> 6;
  const int wr = wid >> 1, wc = wid & 1;
  const int lr = lane & 15;
  const int hg = lane >> 4;
  f32x4 acc[4][4];
#pragma unroll
  for (int a = 0; a < 4; ++a)
#pragma unroll
    for (int c = 0; c < 4; ++c) acc[a][c] = (f32x4){0.f, 0.f, 0.f, 0.f};
  const unsigned short* At[3] = {XH, XL, XH};
  const unsigned short* Bt[3] = {YH, YH, YL};
#pragma unroll
  for (int p = 0; p < 3; ++p) {
#pragma unroll
    for (int s = 0; s < 2; ++s) {
      const int kbyte = s * 64 + hg * 16;
      short8 af[4], bfv[4];
#pragma unroll
      for (int m2 = 0; m2 < 4; ++m2) {
        int row = wr * 64 + m2 * 16 + lr;
        af[m2] = *(const short8*)((const char*)At[p] + row * 128 + (kbyte ^ ((row & 7) << 4)));
      }
#pragma unroll
      for (int n2 = 0; n2 < 4; ++n2) {
        int row = wc * 64 + n2 * 16 + lr;
        bfv[n2] = *(const short8*)((const char*)Bt[p] + row * 128 + (kbyte ^ ((row & 7) << 4)));
      }
#pragma unroll
      for (int m2 = 0; m2 < 4; ++m2)
#pragma unroll
        for (int n2 = 0; n2 < 4; ++n2)
          acc[m2][n2] = __builtin_amdgcn_mfma_f32_16x16x32_bf16(af[m2], bfv[n2], acc[m2][n2], 0, 0, 0);
    }
  }
  const float g = *gptr;
  float yv[4];
#pragma unroll
  for (int n2 = 0; n2 < 4; ++n2) yv[n2] = ysq[j0 + wc * 64 + n2 * 16 + lr];
#pragma unroll
  for (int m2 = 0; m2 < 4; ++m2) {
#pragma unroll
    for (int j = 0; j < 4; ++j) {
      long row = i0 + wr * 64 + m2 * 16 + hg * 4 + j;
      float xr = xsq[row];
      float* op = Out + row * (long)mcols + j0 + wc * 64 + lr;
#pragma unroll
      for (int n2 = 0; n2 < 4; ++n2) {
        float d = fmaxf(xr + yv[n2] - 2.0f * acc[m2][n2][j], 0.f);
        op[n2 * 16] = __expf(-g * d);
      }
    }
  }
}

extern "C" void kernel_launch(void* const* d_in, const int* in_sizes, int n_in,
                              void* d_out, int out_size, void* d_ws, size_t ws_size,
                              hipStream_t stream) {
  const float* x = (const float*)d_in[0];
  const float* y = (const float*)d_in[1];
  const float* g = (const float*)d_in[2];
  float* out = (float*)d_out;

  const int n = in_sizes[0] / DD;   // 8192
  const int m = in_sizes[1] / DD;   // 8192

  const size_t split_bytes = (size_t)(n + m) * DD * 2 * sizeof(unsigned short);
  const size_t needed = split_bytes + (size_t)(n + m) * sizeof(float);

  if (ws_size >= needed && (n % BM) == 0 && (m % (JT * BN)) == 0) {
    unsigned short* XHg = (unsigned short*)d_ws;
    unsigned short* XLg = XHg + (size_t)n * DD;
    unsigned short* YHg = XLg + (size_t)n * DD;
    unsigned short* YLg = YHg + (size_t)m * DD;
    float* xsq = (float*)(YLg + (size_t)m * DD);
    float* ysq = xsq + n;
    prep_split<<<(n + m) / 16, 256, 0, stream>>>(x, y, XHg, XLg, YHg, YLg, xsq, ysq, n);
    dim3 grid(m / (JT * BN), n / BM);   // 16 x 64 = 1024 blocks
    rbf_4t<<<grid, 256, 0, stream>>>(XHg, XLg, YHg, YLg, g, xsq, ysq, out, m);
  } else {
    float* xsq = (float*)d_ws;
    float* ysq = xsq + n;
    prep_sq<<<(n + m) / 16, 256, 0, stream>>>(x, y, xsq, ysq, n);
    dim3 grid2(m / 128, n / 128);
    rbf_mfma_fb<<<grid2, 256, 0, stream>>>(x, y, g, xsq, ysq, out, m);
  }
}

// Round 16
// 63.703 us; speedup vs baseline: 1.0216x; 1.0216x over previous
//
#include <hip/hip_runtime.h>
#include <hip/hip_bf16.h>

// RBF kernel matrix: out[i][j] = exp(-gamma * max(x2[i] + y2[j] - 2*x.y, 0))
//
// Round 16: JT=4 strip with DOUBLE-BUFFERED Y and 1 barrier/tile.
// r15's failure: single-buffered Y needs a WAR sync pair per tile (lgkm
// drain + barrier before DMA, vmcnt+barrier after) -> 2 convoys/tile.
// Fix: X bypasses LDS entirely (fragment-linear direct global loads, r5's
// verified layout) freeing 32KB; Y double-buffers in 2x32KB. Per tile:
// hoist B from buf[t&1] (wave-local, no barrier), issue Y(t+1) DMA into
// buf[(t+1)&1] (sched_barrier pins DMA before stores), 16 fenced sub-tiles
// (6 MFMA + 4 exp + 1 float4 store each), then vmcnt(16) (drains only the
// 8 DMA loads = oldest; the 16 newest = this tile's stores stay in flight)
// + raw s_barrier. One store-less prologue per 256KB of output.
// 3 MFMA passes (hh + loY*hiX + hiY*loX), drop lo*lo (~1e-21 abs err).

#define DD 64
#define BM 128
#define BN 128
#define JT 4

typedef __attribute__((ext_vector_type(8))) short short8;
typedef __attribute__((ext_vector_type(4))) float f32x4;

#if __has_builtin(__builtin_amdgcn_exp2f)
#define EXP2(x) __builtin_amdgcn_exp2f(x)
#else
#define EXP2(x) exp2f(x)
#endif

__device__ __forceinline__ unsigned short f2bf_rne(float f) {
  unsigned u = __float_as_uint(f);
  unsigned r = u + 0x7FFFu + ((u >> 16) & 1u);
  return (unsigned short)(r >> 16);
}

// X fragment-linear index (short8 units): panel p, k-step s, row-block rb.
// Lane hg*16+lr holds row rb*16+lr, k = s*32+hg*8 .. +8.  (r5-verified)
__device__ __forceinline__ long fidx(int p, int s, int rb) {
  return ((((long)p * 2 + s) * 8) + rb) * 64;
}

// ---------------- prep: norms + X->frag-linear, Y->swizzled row images ------
__global__ __launch_bounds__(256)
void prep_mix2(const float* __restrict__ X, const float* __restrict__ Y,
               short8* __restrict__ XHf, short8* __restrict__ XLf,
               unsigned short* __restrict__ YHg, unsigned short* __restrict__ YLg,
               float* __restrict__ xsq, float* __restrict__ ysq, int n) {
  int t = blockIdx.x * 256 + threadIdx.x;
  int row_g = t >> 3;
  int chunk = t & 7;                 // 8 consecutive k per thread
  int isX = (row_g < n);
  int r = isX ? row_g : row_g - n;
  const float* src = (isX ? X : Y) + (long)r * DD + chunk * 8;
  float4 v0 = ((const float4*)src)[0];
  float4 v1 = ((const float4*)src)[1];
  float f[8] = {v0.x, v0.y, v0.z, v0.w, v1.x, v1.y, v1.z, v1.w};

  short8 h8, l8;
  float ss = 0.f;
#pragma unroll
  for (int q = 0; q < 8; ++q) {
    unsigned short h = f2bf_rne(f[q]);
    float hv = __uint_as_float(((unsigned)h) << 16);
    h8[q] = (short)h;
    l8[q] = (short)f2bf_rne(f[q] - hv);
    ss = fmaf(f[q], f[q], ss);
  }
  if (isX) {
    int pn = r >> 7, rb = (r >> 4) & 7, lr = r & 15;
    int s = chunk >> 2, hg = chunk & 3;
    long o = fidx(pn, s, rb) + hg * 16 + lr;
    XHf[o] = h8;
    XLf[o] = l8;
  } else {
    int sw = (chunk * 16) ^ ((r & 7) << 4);   // swizzled byte offset (r7-verified)
    *(short8*)((char*)YHg + (long)r * 128 + sw) = h8;
    *(short8*)((char*)YLg + (long)r * 128 + sw) = l8;
  }
  ss += __shfl_xor(ss, 1);
  ss += __shfl_xor(ss, 2);
  ss += __shfl_xor(ss, 4);
  if (chunk == 0) (isX ? xsq : ysq)[r] = ss;
}

// ---------------- main: JT=4, Y double-buffer, fenced sub-tile stores -------
__global__ __launch_bounds__(256, 2)
void rbf_db(const short8* __restrict__ XHf, const short8* __restrict__ XLf,
            const unsigned short* __restrict__ YHg, const unsigned short* __restrict__ YLg,
            const float* __restrict__ gptr,
            const float* __restrict__ xsq, const float* __restrict__ ysq,
            float* __restrict__ Out, int mcols) {
  // buf0: [0,16K) YH  [16K,32K) YL ; buf1: [32K,48K) YH  [48K,64K) YL
  __shared__ __align__(128) char lds[65536];

  const int tid = threadIdx.x;
  const int lane = tid & 63;
  const int wid = tid >> 6;        // 0..3
  const int ip = blockIdx.y;       // X panel (128 rows)
  const long i0 = (long)ip * BM;
  const long j0base = (long)blockIdx.x * (JT * BN);   // 512-col strip

  // ---- prologue: Y0 DMA into buf0 (8 loads/thread, issued first = oldest)
#pragma unroll
  for (int it = 0; it < 4; ++it) {
    int off = it * 4096 + wid * 1024;           // wave-uniform
    __builtin_amdgcn_global_load_lds(
        (const __attribute__((address_space(1))) void*)((const char*)YHg + j0base * 128 + off + lane * 16),
        (__attribute__((address_space(3))) void*)(lds + off), 16, 0, 0);
    __builtin_amdgcn_global_load_lds(
        (const __attribute__((address_space(1))) void*)((const char*)YLg + j0base * 128 + off + lane * 16),
        (__attribute__((address_space(3))) void*)(lds + 16384 + off), 16, 0, 0);
  }

  const int wr = wid >> 1, wc = wid & 1;
  const int lr = lane & 15;
  const int hg = lane >> 4;        // 0..3

  // ---- A-frags direct from global (frag-linear, coalesced dwordx4)
  short8 afh[2][4], afl[2][4];     // [s][m2]
#pragma unroll
  for (int s = 0; s < 2; ++s)
#pragma unroll
    for (int q = 0; q < 4; ++q) {
      afh[s][q] = XHf[fidx(ip, s, wr * 4 + q) + lane];
      afl[s][q] = XLf[fidx(ip, s, wr * 4 + q) + lane];
    }

  const float g = *gptr;
  const float cf = -g * 1.4426950408889634f;   // -gamma*log2(e)
  const float nc2 = -2.0f * cf;
  float cxr[4];
#pragma unroll
  for (int m2 = 0; m2 < 4; ++m2) cxr[m2] = cf * xsq[i0 + wr * 64 + m2 * 16 + lr];

  __syncthreads();   // drains prologue DMA + A-frag loads (no stores yet)

#pragma unroll
  for (int t = 0; t < JT; ++t) {
    const long j0 = j0base + (long)t * BN;
    const int yb = (t & 1) ? 32768 : 0;

    // ---- hoist B(t) frags from buf[t&1] (wave-local; no barrier needed)
    short8 bfh[2][4], bfl[2][4];   // [s][n2]
#pragma unroll
    for (int s = 0; s < 2; ++s)
#pragma unroll
      for (int q = 0; q < 4; ++q) {
        int rb = wc * 64 + q * 16 + lr;
        int ob = (s * 64 + hg * 16) ^ ((rb & 7) << 4);
        bfh[s][q] = *(const short8*)(lds + yb + rb * 128 + ob);
        bfl[s][q] = *(const short8*)(lds + yb + 16384 + rb * 128 + ob);
      }

    // ---- issue Y(t+1) DMA into the other buffer (no WAR hazard: its last
    // readers finished before the previous tile's arrival barrier)
    if (t + 1 < JT) {
      const int yn = ((t + 1) & 1) ? 32768 : 0;
      const char* yh = (const char*)YHg + (j0 + BN) * 128;
      const char* yl = (const char*)YLg + (j0 + BN) * 128;
#pragma unroll
      for (int it = 0; it < 4; ++it) {
        int off = it * 4096 + wid * 1024;
        __builtin_amdgcn_global_load_lds(
            (const __attribute__((address_space(1))) void*)(yh + off + lane * 16),
            (__attribute__((address_space(3))) void*)(lds + yn + off), 16, 0, 0);
        __builtin_amdgcn_global_load_lds(
            (const __attribute__((address_space(1))) void*)(yl + off + lane * 16),
            (__attribute__((address_space(3))) void*)(lds + yn + 16384 + off), 16, 0, 0);
      }
      __builtin_amdgcn_sched_barrier(0);   // pin: DMA issues before any store
    }

    // ---- 16 fenced sub-tiles: 6 MFMAs + 4 exp + 1 float4 store each
    float4 cyv[4];
#pragma unroll
    for (int n2 = 0; n2 < 4; ++n2) {
      float4 yq = *(const float4*)&ysq[j0 + wc * 64 + n2 * 16 + hg * 4];
      cyv[n2] = make_float4(cf * yq.x, cf * yq.y, cf * yq.z, cf * yq.w);
    }
#pragma unroll
    for (int m2 = 0; m2 < 4; ++m2) {
      long row = i0 + wr * 64 + m2 * 16 + lr;
      float* op = Out + row * (long)mcols + j0 + wc * 64 + hg * 4;
#pragma unroll
      for (int n2 = 0; n2 < 4; ++n2) {
        f32x4 a = (f32x4){0.f, 0.f, 0.f, 0.f};
#pragma unroll
        for (int s = 0; s < 2; ++s) {
          a = __builtin_amdgcn_mfma_f32_16x16x32_bf16(bfh[s][n2], afh[s][m2], a, 0, 0, 0);
          a = __builtin_amdgcn_mfma_f32_16x16x32_bf16(bfh[s][n2], afl[s][m2], a, 0, 0, 0);
          a = __builtin_amdgcn_mfma_f32_16x16x32_bf16(bfl[s][n2], afh[s][m2], a, 0, 0, 0);
        }
        float o[4];
        o[0] = EXP2(fminf(fmaf(nc2, a[0], cxr[m2] + cyv[n2].x), 0.f));
        o[1] = EXP2(fminf(fmaf(nc2, a[1], cxr[m2] + cyv[n2].y), 0.f));
        o[2] = EXP2(fminf(fmaf(nc2, a[2], cxr[m2] + cyv[n2].z), 0.f));
        o[3] = EXP2(fminf(fmaf(nc2, a[3], cxr[m2] + cyv[n2].w), 0.f));
        *(float4*)(op + n2 * 16) = *(float4*)o;
        __builtin_amdgcn_sched_barrier(0);   // pin store spacing
      }
    }

    // ---- arrival sync for Y(t+1): wait ONLY the 8 DMA loads (oldest);
    // this tile's 16 stores (newest) stay in flight. Raw barrier: no drain.
    if (t + 1 < JT) {
      asm volatile("s_waitcnt vmcnt(16)" ::: "memory");
      __builtin_amdgcn_s_barrier();
    }
  }
}

// ---------------- fallback (proven round-2 path) ---------------------------
__global__ __launch_bounds__(256)
void prep_sq(const float* __restrict__ X, const float* __restrict__ Y,
             float* __restrict__ xsq, float* __restrict__ ysq, int n) {
  int t = blockIdx.x * 256 + threadIdx.x;
  int row = t >> 4;
  int c = t & 15;
  const float* src;
  float* dst;
  if (row < n) { src = X + (long)row * DD; dst = xsq + row; }
  else         { src = Y + (long)(row - n) * DD; dst = ysq + (row - n); }
  float4 v = ((const float4*)src)[c];
  float s = v.x * v.x + v.y * v.y + v.z * v.z + v.w * v.w;
  s += __shfl_xor(s, 1);
  s += __shfl_xor(s, 2);
  s += __shfl_xor(s, 4);
  s += __shfl_xor(s, 8);
  if (c == 0) *dst = s;
}

__global__ __launch_bounds__(256, 2)
void rbf_mfma_fb(const float* __restrict__ X, const float* __restrict__ Y,
                 const float* __restrict__ gptr,
                 const float* __restrict__ xsq, const float* __restrict__ ysq,
                 float* __restrict__ Out, int mcols) {
  __shared__ unsigned short XH[128 * DD], XL[128 * DD];
  __shared__ unsigned short YH[128 * DD], YL[128 * DD];
  const int tid = threadIdx.x;
  const long i0 = (long)blockIdx.y * 128;
  const long j0 = (long)blockIdx.x * 128;
#pragma unroll
  for (int it = 0; it < 16; ++it) {
    int e = it * 256 + tid;
    int half = e >> 11;
    int idx = e & 2047;
    int row = idx >> 4;
    int c4 = idx & 15;
    const float* src = half ? (Y + (j0 + row) * DD) : (X + (i0 + row) * DD);
    float4 v = ((const float4*)src)[c4];
    float f[4] = {v.x, v.y, v.z, v.w};
    unsigned short h[4], l[4];
#pragma unroll
    for (int q = 0; q < 4; ++q) {
      h[q] = f2bf_rne(f[q]);
      float hv = __uint_as_float(((unsigned)h[q]) << 16);
      l[q] = f2bf_rne(f[q] - hv);
    }
    int sw = (c4 * 8) ^ ((row & 7) << 4);
    unsigned short* Ht = half ? YH : XH;
    unsigned short* Lt = half ? YL : XL;
    *(ushort4*)((char*)Ht + row * 128 + sw) = make_ushort4(h[0], h[1], h[2], h[3]);
    *(ushort4*)((char*)Lt + row * 128 + sw) = make_ushort4(l[0], l[1], l[2], l[3]);
  }
  __syncthreads();
  const int lane = tid & 63;
  const int wid = tid >> 6;
  const int wr = wid >> 1, wc = wid & 1;
  const int lr = lane & 15;
  const int hg = lane >> 4;
  f32x4 acc[4][4];
#pragma unroll
  for (int a = 0; a < 4; ++a)
#pragma unroll
    for (int c = 0; c < 4; ++c) acc[a][c] = (f32x4){0.f, 0.f, 0.f, 0.f};
  const unsigned short* At[3] = {XH, XL, XH};
  const unsigned short* Bt[3] = {YH, YH, YL};
#pragma unroll
  for (int p = 0; p < 3; ++p) {
#pragma unroll
    for (int s = 0; s < 2; ++s) {
      const int kbyte = s * 64 + hg * 16;
      short8 af[4], bfv[4];
#pragma unroll
      for (int m2 = 0; m2 < 4; ++m2) {
        int row = wr * 64 + m2 * 16 + lr;
        af[m2] = *(const short8*)((const char*)At[p] + row * 128 + (kbyte ^ ((row & 7) << 4)));
      }
#pragma unroll
      for (int n2 = 0; n2 < 4; ++n2) {
        int row = wc * 64 + n2 * 16 + lr;
        bfv[n2] = *(const short8*)((const char*)Bt[p] + row * 128 + (kbyte ^ ((row & 7) << 4)));
      }
#pragma unroll
      for (int m2 = 0; m2 < 4; ++m2)
#pragma unroll
        for (int n2 = 0; n2 < 4; ++n2)
          acc[m2][n2] = __builtin_amdgcn_mfma_f32_16x16x32_bf16(af[m2], bfv[n2], acc[m2][n2], 0, 0, 0);
    }
  }
  const float g = *gptr;
  float yv[4];
#pragma unroll
  for (int n2 = 0; n2 < 4; ++n2) yv[n2] = ysq[j0 + wc * 64 + n2 * 16 + lr];
#pragma unroll
  for (int m2 = 0; m2 < 4; ++m2) {
#pragma unroll
    for (int j = 0; j < 4; ++j) {
      long row = i0 + wr * 64 + m2 * 16 + hg * 4 + j;
      float xr = xsq[row];
      float* op = Out + row * (long)mcols + j0 + wc * 64 + lr;
#pragma unroll
      for (int n2 = 0; n2 < 4; ++n2) {
        float d = fmaxf(xr + yv[n2] - 2.0f * acc[m2][n2][j], 0.f);
        op[n2 * 16] = __expf(-g * d);
      }
    }
  }
}

extern "C" void kernel_launch(void* const* d_in, const int* in_sizes, int n_in,
                              void* d_out, int out_size, void* d_ws, size_t ws_size,
                              hipStream_t stream) {
  const float* x = (const float*)d_in[0];
  const float* y = (const float*)d_in[1];
  const float* g = (const float*)d_in[2];
  float* out = (float*)d_out;

  const int n = in_sizes[0] / DD;   // 8192
  const int m = in_sizes[1] / DD;   // 8192

  const size_t split_bytes = (size_t)(n + m) * DD * 2 * sizeof(unsigned short);
  const size_t needed = split_bytes + (size_t)(n + m) * sizeof(float);

  if (ws_size >= needed && (n % BM) == 0 && (m % (JT * BN)) == 0) {
    short8* XHf = (short8*)d_ws;                       // n*DD/8 short8
    short8* XLf = XHf + (size_t)n * DD / 8;
    unsigned short* YHg = (unsigned short*)(XLf + (size_t)n * DD / 8);
    unsigned short* YLg = YHg + (size_t)m * DD;
    float* xsq = (float*)(YLg + (size_t)m * DD);
    float* ysq = xsq + n;
    prep_mix2<<<(n + m) * 8 / 256, 256, 0, stream>>>(x, y, XHf, XLf, YHg, YLg, xsq, ysq, n);
    dim3 grid(m / (JT * BN), n / BM);   // 16 x 64 = 1024 blocks
    rbf_db<<<grid, 256, 0, stream>>>(XHf, XLf, YHg, YLg, g, xsq, ysq, out, m);
  } else {
    float* xsq = (float*)d_ws;
    float* ysq = xsq + n;
    prep_sq<<<(n + m) / 16, 256, 0, stream>>>(x, y, xsq, ysq, n);
    dim3 grid2(m / 128, n / 128);
    rbf_mfma_fb<<<grid2, 256, 0, stream>>>(x, y, g, xsq, ysq, out, m);
  }
}

// Round 17
// 55.024 us; speedup vs baseline: 1.1827x; 1.1577x over previous
//
#include <hip/hip_runtime.h>
#include <hip/hip_bf16.h>

// RBF kernel matrix: out[i][j] = exp(-gamma * max(x2[i] + y2[j] - 2*x.y, 0))
//
// Round 17: r14 (54.5us best) minus its one mid-kernel convoy.
// r16's lesson: ANY mid-kernel vmcnt that must see DMA completion also
// drains older in-flight stores (age-ordered queue) -> convoys. So: no
// mid-kernel waits at all. Prologue stages BOTH Y tiles (4x16KB = 64KB LDS);
// X frags come DIRECT from global in r5's verified fragment-linear layout
// (32 coalesced dwordx4, zero LDS). One __syncthreads (only prologue loads
// outstanding -> free), then tile0's 16 fenced sub-tiles, then tile1's,
// NO barrier between (tile1's LDS written before the sync, never reused;
// B-hoist is wave-local). Entire post-sync block life = store-interleaved
// stream. 3 MFMA passes (hh + loY*hiX + hiY*loX), drop lo*lo (~1e-21 err).

#define DD 64
#define BM 128
#define BN 128

typedef __attribute__((ext_vector_type(8))) short short8;
typedef __attribute__((ext_vector_type(4))) float f32x4;

#if __has_builtin(__builtin_amdgcn_exp2f)
#define EXP2(x) __builtin_amdgcn_exp2f(x)
#else
#define EXP2(x) exp2f(x)
#endif

__device__ __forceinline__ unsigned short f2bf_rne(float f) {
  unsigned u = __float_as_uint(f);
  unsigned r = u + 0x7FFFu + ((u >> 16) & 1u);
  return (unsigned short)(r >> 16);
}

// X fragment-linear index (short8 units): panel p, k-step s, row-block rb.
// Lane hg*16+lr holds row rb*16+lr, k = s*32+hg*8 .. +8.  (r5-verified)
__device__ __forceinline__ long fidx(int p, int s, int rb) {
  return ((((long)p * 2 + s) * 8) + rb) * 64;
}

// ---------------- prep: norms + X->frag-linear, Y->swizzled row images ------
__global__ __launch_bounds__(256)
void prep_mix2(const float* __restrict__ X, const float* __restrict__ Y,
               short8* __restrict__ XHf, short8* __restrict__ XLf,
               unsigned short* __restrict__ YHg, unsigned short* __restrict__ YLg,
               float* __restrict__ xsq, float* __restrict__ ysq, int n) {
  int t = blockIdx.x * 256 + threadIdx.x;
  int row_g = t >> 3;
  int chunk = t & 7;                 // 8 consecutive k per thread
  int isX = (row_g < n);
  int r = isX ? row_g : row_g - n;
  const float* src = (isX ? X : Y) + (long)r * DD + chunk * 8;
  float4 v0 = ((const float4*)src)[0];
  float4 v1 = ((const float4*)src)[1];
  float f[8] = {v0.x, v0.y, v0.z, v0.w, v1.x, v1.y, v1.z, v1.w};

  short8 h8, l8;
  float ss = 0.f;
#pragma unroll
  for (int q = 0; q < 8; ++q) {
    unsigned short h = f2bf_rne(f[q]);
    float hv = __uint_as_float(((unsigned)h) << 16);
    h8[q] = (short)h;
    l8[q] = (short)f2bf_rne(f[q] - hv);
    ss = fmaf(f[q], f[q], ss);
  }
  if (isX) {
    int pn = r >> 7, rb = (r >> 4) & 7, lr = r & 15;
    int s = chunk >> 2, hg = chunk & 3;
    long o = fidx(pn, s, rb) + hg * 16 + lr;
    XHf[o] = h8;
    XLf[o] = l8;
  } else {
    int sw = (chunk * 16) ^ ((r & 7) << 4);   // swizzled byte offset (verified)
    *(short8*)((char*)YHg + (long)r * 128 + sw) = h8;
    *(short8*)((char*)YLg + (long)r * 128 + sw) = l8;
  }
  ss += __shfl_xor(ss, 1);
  ss += __shfl_xor(ss, 2);
  ss += __shfl_xor(ss, 4);
  if (chunk == 0) (isX ? xsq : ysq)[r] = ss;
}

// ---------------- main: 2 tiles all-staged-up-front, zero mid-kernel syncs --
__global__ __launch_bounds__(256, 2)
void rbf_noconvoy(const short8* __restrict__ XHf, const short8* __restrict__ XLf,
                  const unsigned short* __restrict__ YHg, const unsigned short* __restrict__ YLg,
                  const float* __restrict__ gptr,
                  const float* __restrict__ xsq, const float* __restrict__ ysq,
                  float* __restrict__ Out, int mcols) {
  // [0,16K) Y0H  [16K,32K) Y0L  [32K,48K) Y1H  [48K,64K) Y1L
  __shared__ __align__(128) char lds[65536];

  const int tid = threadIdx.x;
  const int lane = tid & 63;
  const int wid = tid >> 6;        // 0..3
  const int ip = blockIdx.y;       // X panel (128 rows)
  const long i0 = (long)ip * BM;
  const long j0 = (long)blockIdx.x * (2 * BN);   // 256-col strip

  // ---- prologue DMA: Y0H, Y0L, Y1H, Y1L (16 KB each)
  const char* srcs[4] = {(const char*)YHg + j0 * 128,        (const char*)YLg + j0 * 128,
                         (const char*)YHg + (j0 + BN) * 128, (const char*)YLg + (j0 + BN) * 128};
#pragma unroll
  for (int t4 = 0; t4 < 4; ++t4) {
#pragma unroll
    for (int it = 0; it < 4; ++it) {
      int off = it * 4096 + wid * 1024;           // wave-uniform
      __builtin_amdgcn_global_load_lds(
          (const __attribute__((address_space(1))) void*)(srcs[t4] + off + lane * 16),
          (__attribute__((address_space(3))) void*)(lds + t4 * 16384 + off),
          16, 0, 0);
    }
  }

  const int wr = wid >> 1, wc = wid & 1;
  const int lr = lane & 15;
  const int hg = lane >> 4;        // 0..3

  // ---- A-frags direct from global (frag-linear, coalesced dwordx4)
  short8 afh[2][4], afl[2][4];     // [s][m2]
#pragma unroll
  for (int s = 0; s < 2; ++s)
#pragma unroll
    for (int q = 0; q < 4; ++q) {
      afh[s][q] = XHf[fidx(ip, s, wr * 4 + q) + lane];
      afl[s][q] = XLf[fidx(ip, s, wr * 4 + q) + lane];
    }

  const float g = *gptr;
  const float cf = -g * 1.4426950408889634f;   // -gamma*log2(e)
  const float nc2 = -2.0f * cf;
  float cxr[4];
#pragma unroll
  for (int m2 = 0; m2 < 4; ++m2) cxr[m2] = cf * xsq[i0 + wr * 64 + m2 * 16 + lr];

  __syncthreads();   // drains prologue loads only (no stores yet) — cheap

  // ---- two tiles, no syncs between: pure store-interleaved stream
#pragma unroll
  for (int t = 0; t < 2; ++t) {
    const long jt = j0 + (long)t * BN;
    const int yb = t * 32768;

    // hoist B(t) frags (wave-local LDS reads; data never overwritten)
    short8 bfh[2][4], bfl[2][4];   // [s][n2]
#pragma unroll
    for (int s = 0; s < 2; ++s)
#pragma unroll
      for (int q = 0; q < 4; ++q) {
        int rb = wc * 64 + q * 16 + lr;
        int ob = (s * 64 + hg * 16) ^ ((rb & 7) << 4);
        bfh[s][q] = *(const short8*)(lds + yb + rb * 128 + ob);
        bfl[s][q] = *(const short8*)(lds + yb + 16384 + rb * 128 + ob);
      }

    float4 cyv[4];
#pragma unroll
    for (int n2 = 0; n2 < 4; ++n2) {
      float4 yq = *(const float4*)&ysq[jt + wc * 64 + n2 * 16 + hg * 4];
      cyv[n2] = make_float4(cf * yq.x, cf * yq.y, cf * yq.z, cf * yq.w);
    }

    // 16 fenced sub-tiles: 6 MFMAs + 4 exp + 1 float4 store each
#pragma unroll
    for (int m2 = 0; m2 < 4; ++m2) {
      long row = i0 + wr * 64 + m2 * 16 + lr;
      float* op = Out + row * (long)mcols + jt + wc * 64 + hg * 4;
#pragma unroll
      for (int n2 = 0; n2 < 4; ++n2) {
        f32x4 a = (f32x4){0.f, 0.f, 0.f, 0.f};
#pragma unroll
        for (int s = 0; s < 2; ++s) {
          a = __builtin_amdgcn_mfma_f32_16x16x32_bf16(bfh[s][n2], afh[s][m2], a, 0, 0, 0);
          a = __builtin_amdgcn_mfma_f32_16x16x32_bf16(bfh[s][n2], afl[s][m2], a, 0, 0, 0);
          a = __builtin_amdgcn_mfma_f32_16x16x32_bf16(bfl[s][n2], afh[s][m2], a, 0, 0, 0);
        }
        float o[4];
        o[0] = EXP2(fminf(fmaf(nc2, a[0], cxr[m2] + cyv[n2].x), 0.f));
        o[1] = EXP2(fminf(fmaf(nc2, a[1], cxr[m2] + cyv[n2].y), 0.f));
        o[2] = EXP2(fminf(fmaf(nc2, a[2], cxr[m2] + cyv[n2].z), 0.f));
        o[3] = EXP2(fminf(fmaf(nc2, a[3], cxr[m2] + cyv[n2].w), 0.f));
        *(float4*)(op + n2 * 16) = *(float4*)o;
        __builtin_amdgcn_sched_barrier(0);   // pin store spacing
      }
    }
  }
}

// ---------------- fallback (proven round-2 path) ---------------------------
__global__ __launch_bounds__(256)
void prep_sq(const float* __restrict__ X, const float* __restrict__ Y,
             float* __restrict__ xsq, float* __restrict__ ysq, int n) {
  int t = blockIdx.x * 256 + threadIdx.x;
  int row = t >> 4;
  int c = t & 15;
  const float* src;
  float* dst;
  if (row < n) { src = X + (long)row * DD; dst = xsq + row; }
  else         { src = Y + (long)(row - n) * DD; dst = ysq + (row - n); }
  float4 v = ((const float4*)src)[c];
  float s = v.x * v.x + v.y * v.y + v.z * v.z + v.w * v.w;
  s += __shfl_xor(s, 1);
  s += __shfl_xor(s, 2);
  s += __shfl_xor(s, 4);
  s += __shfl_xor(s, 8);
  if (c == 0) *dst = s;
}

__global__ __launch_bounds__(256, 2)
void rbf_mfma_fb(const float* __restrict__ X, const float* __restrict__ Y,
                 const float* __restrict__ gptr,
                 const float* __restrict__ xsq, const float* __restrict__ ysq,
                 float* __restrict__ Out, int mcols) {
  __shared__ unsigned short XH[128 * DD], XL[128 * DD];
  __shared__ unsigned short YH[128 * DD], YL[128 * DD];
  const int tid = threadIdx.x;
  const long i0 = (long)blockIdx.y * 128;
  const long j0 = (long)blockIdx.x * 128;
#pragma unroll
  for (int it = 0; it < 16; ++it) {
    int e = it * 256 + tid;
    int half = e >> 11;
    int idx = e & 2047;
    int row = idx >> 4;
    int c4 = idx & 15;
    const float* src = half ? (Y + (j0 + row) * DD) : (X + (i0 + row) * DD);
    float4 v = ((const float4*)src)[c4];
    float f[4] = {v.x, v.y, v.z, v.w};
    unsigned short h[4], l[4];
#pragma unroll
    for (int q = 0; q < 4; ++q) {
      h[q] = f2bf_rne(f[q]);
      float hv = __uint_as_float(((unsigned)h[q]) << 16);
      l[q] = f2bf_rne(f[q] - hv);
    }
    int sw = (c4 * 8) ^ ((row & 7) << 4);
    unsigned short* Ht = half ? YH : XH;
    unsigned short* Lt = half ? YL : XL;
    *(ushort4*)((char*)Ht + row * 128 + sw) = make_ushort4(h[0], h[1], h[2], h[3]);
    *(ushort4*)((char*)Lt + row * 128 + sw) = make_ushort4(l[0], l[1], l[2], l[3]);
  }
  __syncthreads();
  const int lane = tid & 63;
  const int wid = tid >> 6;
  const int wr = wid >> 1, wc = wid & 1;
  const int lr = lane & 15;
  const int hg = lane >> 4;
  f32x4 acc[4][4];
#pragma unroll
  for (int a = 0; a < 4; ++a)
#pragma unroll
    for (int c = 0; c < 4; ++c) acc[a][c] = (f32x4){0.f, 0.f, 0.f, 0.f};
  const unsigned short* At[3] = {XH, XL, XH};
  const unsigned short* Bt[3] = {YH, YH, YL};
#pragma unroll
  for (int p = 0; p < 3; ++p) {
#pragma unroll
    for (int s = 0; s < 2; ++s) {
      const int kbyte = s * 64 + hg * 16;
      short8 af[4], bfv[4];
#pragma unroll
      for (int m2 = 0; m2 < 4; ++m2) {
        int row = wr * 64 + m2 * 16 + lr;
        af[m2] = *(const short8*)((const char*)At[p] + row * 128 + (kbyte ^ ((row & 7) << 4)));
      }
#pragma unroll
      for (int n2 = 0; n2 < 4; ++n2) {
        int row = wc * 64 + n2 * 16 + lr;
        bfv[n2] = *(const short8*)((const char*)Bt[p] + row * 128 + (kbyte ^ ((row & 7) << 4)));
      }
#pragma unroll
      for (int m2 = 0; m2 < 4; ++m2)
#pragma unroll
        for (int n2 = 0; n2 < 4; ++n2)
          acc[m2][n2] = __builtin_amdgcn_mfma_f32_16x16x32_bf16(af[m2], bfv[n2], acc[m2][n2], 0, 0, 0);
    }
  }
  const float g = *gptr;
  float yv[4];
#pragma unroll
  for (int n2 = 0; n2 < 4; ++n2) yv[n2] = ysq[j0 + wc * 64 + n2 * 16 + lr];
#pragma unroll
  for (int m2 = 0; m2 < 4; ++m2) {
#pragma unroll
    for (int j = 0; j < 4; ++j) {
      long row = i0 + wr * 64 + m2 * 16 + hg * 4 + j;
      float xr = xsq[row];
      float* op = Out + row * (long)mcols + j0 + wc * 64 + lr;
#pragma unroll
      for (int n2 = 0; n2 < 4; ++n2) {
        float d = fmaxf(xr + yv[n2] - 2.0f * acc[m2][n2][j], 0.f);
        op[n2 * 16] = __expf(-g * d);
      }
    }
  }
}

extern "C" void kernel_launch(void* const* d_in, const int* in_sizes, int n_in,
                              void* d_out, int out_size, void* d_ws, size_t ws_size,
                              hipStream_t stream) {
  const float* x = (const float*)d_in[0];
  const float* y = (const float*)d_in[1];
  const float* g = (const float*)d_in[2];
  float* out = (float*)d_out;

  const int n = in_sizes[0] / DD;   // 8192
  const int m = in_sizes[1] / DD;   // 8192

  const size_t split_bytes = (size_t)(n + m) * DD * 2 * sizeof(unsigned short);
  const size_t needed = split_bytes + (size_t)(n + m) * sizeof(float);

  if (ws_size >= needed && (n % BM) == 0 && (m % (2 * BN)) == 0) {
    short8* XHf = (short8*)d_ws;                       // n*DD/8 short8
    short8* XLf = XHf + (size_t)n * DD / 8;
    unsigned short* YHg = (unsigned short*)(XLf + (size_t)n * DD / 8);
    unsigned short* YLg = YHg + (size_t)m * DD;
    float* xsq = (float*)(YLg + (size_t)m * DD);
    float* ysq = xsq + n;
    prep_mix2<<<(n + m) * 8 / 256, 256, 0, stream>>>(x, y, XHf, XLf, YHg, YLg, xsq, ysq, n);
    dim3 grid(m / (2 * BN), n / BM);   // 32 x 64 = 2048 blocks
    rbf_noconvoy<<<grid, 256, 0, stream>>>(XHf, XLf, YHg, YLg, g, xsq, ysq, out, m);
  } else {
    float* xsq = (float*)d_ws;
    float* ysq = xsq + n;
    prep_sq<<<(n + m) / 16, 256, 0, stream>>>(x, y, xsq, ysq, n);
    dim3 grid2(m / 128, n / 128);
    rbf_mfma_fb<<<grid2, 256, 0, stream>>>(x, y, g, xsq, ysq, out, m);
  }
}

// Round 18
// 52.180 us; speedup vs baseline: 1.2472x; 1.0545x over previous
//
#include <hip/hip_runtime.h>
#include <hip/hip_bf16.h>

// RBF kernel matrix: out[i][j] = exp(-gamma * max(x2[i] + y2[j] - 2*x.y, 0))
//
// Round 18: persistent i-sweep. Block stages its Y strip (2 tiles, 64KB)
// ONCE; X frags come direct from global (frag-linear, L2-resident) so LDS
// is never rewritten -> ZERO barriers after the single prologue sync.
// Block sweeps IPB=4 X panels (512 KB output per prologue, 4x r14), grid
// 32x16 = 512 blocks = exactly 2/CU (no tail generations). Per panel the
// only stall is 32 independent L2 frag loads (compiler waitcnt also drains
// the previous panel's last store acks -- mild, no barrier, 8 waves cover).
// Fenced sub-tile epilogue (r12): 6 MFMA + 4 exp + 1 float4 store, pinned.
// 3 MFMA passes (hh + loY*hiX + hiY*loX), drop lo*lo (~1e-21 abs err).

#define DD 64
#define BM 128
#define BN 128
#define IPB 4

typedef __attribute__((ext_vector_type(8))) short short8;
typedef __attribute__((ext_vector_type(4))) float f32x4;

#if __has_builtin(__builtin_amdgcn_exp2f)
#define EXP2(x) __builtin_amdgcn_exp2f(x)
#else
#define EXP2(x) exp2f(x)
#endif

__device__ __forceinline__ unsigned short f2bf_rne(float f) {
  unsigned u = __float_as_uint(f);
  unsigned r = u + 0x7FFFu + ((u >> 16) & 1u);
  return (unsigned short)(r >> 16);
}

// X fragment-linear index (short8 units): panel p, k-step s, row-block rb.
// Lane hg*16+lr holds row rb*16+lr, k = s*32+hg*8 .. +8.  (r5-verified)
__device__ __forceinline__ long fidx(int p, int s, int rb) {
  return ((((long)p * 2 + s) * 8) + rb) * 64;
}

// ---------------- prep: norms + X->frag-linear, Y->swizzled row images ------
__global__ __launch_bounds__(256)
void prep_mix2(const float* __restrict__ X, const float* __restrict__ Y,
               short8* __restrict__ XHf, short8* __restrict__ XLf,
               unsigned short* __restrict__ YHg, unsigned short* __restrict__ YLg,
               float* __restrict__ xsq, float* __restrict__ ysq, int n) {
  int t = blockIdx.x * 256 + threadIdx.x;
  int row_g = t >> 3;
  int chunk = t & 7;                 // 8 consecutive k per thread
  int isX = (row_g < n);
  int r = isX ? row_g : row_g - n;
  const float* src = (isX ? X : Y) + (long)r * DD + chunk * 8;
  float4 v0 = ((const float4*)src)[0];
  float4 v1 = ((const float4*)src)[1];
  float f[8] = {v0.x, v0.y, v0.z, v0.w, v1.x, v1.y, v1.z, v1.w};

  short8 h8, l8;
  float ss = 0.f;
#pragma unroll
  for (int q = 0; q < 8; ++q) {
    unsigned short h = f2bf_rne(f[q]);
    float hv = __uint_as_float(((unsigned)h) << 16);
    h8[q] = (short)h;
    l8[q] = (short)f2bf_rne(f[q] - hv);
    ss = fmaf(f[q], f[q], ss);
  }
  if (isX) {
    int pn = r >> 7, rb = (r >> 4) & 7, lr = r & 15;
    int s = chunk >> 2, hg = chunk & 3;
    long o = fidx(pn, s, rb) + hg * 16 + lr;
    XHf[o] = h8;
    XLf[o] = l8;
  } else {
    int sw = (chunk * 16) ^ ((r & 7) << 4);   // swizzled byte offset (verified)
    *(short8*)((char*)YHg + (long)r * 128 + sw) = h8;
    *(short8*)((char*)YLg + (long)r * 128 + sw) = l8;
  }
  ss += __shfl_xor(ss, 1);
  ss += __shfl_xor(ss, 2);
  ss += __shfl_xor(ss, 4);
  if (chunk == 0) (isX ? xsq : ysq)[r] = ss;
}

// ---------------- main: persistent i-sweep, zero post-sync barriers ---------
__global__ __launch_bounds__(256, 2)
void rbf_isweep(const short8* __restrict__ XHf, const short8* __restrict__ XLf,
                const unsigned short* __restrict__ YHg, const unsigned short* __restrict__ YLg,
                const float* __restrict__ gptr,
                const float* __restrict__ xsq, const float* __restrict__ ysq,
                float* __restrict__ Out, int mcols) {
  // [0,16K) Y0H  [16K,32K) Y0L  [32K,48K) Y1H  [48K,64K) Y1L — never rewritten
  __shared__ __align__(128) char lds[65536];

  const int tid = threadIdx.x;
  const int lane = tid & 63;
  const int wid = tid >> 6;        // 0..3
  const int ig0 = blockIdx.y * IPB;              // first X panel
  const long j0 = (long)blockIdx.x * (2 * BN);   // 256-col strip

  // ---- prologue DMA: Y0H, Y0L, Y1H, Y1L (16 KB each)
  const char* srcs[4] = {(const char*)YHg + j0 * 128,        (const char*)YLg + j0 * 128,
                         (const char*)YHg + (j0 + BN) * 128, (const char*)YLg + (j0 + BN) * 128};
#pragma unroll
  for (int t4 = 0; t4 < 4; ++t4) {
#pragma unroll
    for (int it = 0; it < 4; ++it) {
      int off = it * 4096 + wid * 1024;           // wave-uniform
      __builtin_amdgcn_global_load_lds(
          (const __attribute__((address_space(1))) void*)(srcs[t4] + off + lane * 16),
          (__attribute__((address_space(3))) void*)(lds + t4 * 16384 + off),
          16, 0, 0);
    }
  }

  const int wr = wid >> 1, wc = wid & 1;
  const int lr = lane & 15;
  const int hg = lane >> 4;        // 0..3

  // ---- A-frags for panel 0 (direct from global; overlaps the Y DMA)
  short8 afh[2][4], afl[2][4];     // [s][m2]
#pragma unroll
  for (int s = 0; s < 2; ++s)
#pragma unroll
    for (int q = 0; q < 4; ++q) {
      afh[s][q] = XHf[fidx(ig0, s, wr * 4 + q) + lane];
      afl[s][q] = XLf[fidx(ig0, s, wr * 4 + q) + lane];
    }

  const float g = *gptr;
  const float cf = -g * 1.4426950408889634f;   // -gamma*log2(e)
  const float nc2 = -2.0f * cf;

  __syncthreads();   // drains prologue loads only (no stores yet) — cheap

  for (int p = 0; p < IPB; ++p) {
    const int ip = ig0 + p;
    const long i0 = (long)ip * BM;
    float cxr[4];
#pragma unroll
    for (int m2 = 0; m2 < 4; ++m2) cxr[m2] = cf * xsq[i0 + wr * 64 + m2 * 16 + lr];

#pragma unroll
    for (int t = 0; t < 2; ++t) {
      const long jt = j0 + (long)t * BN;
      const int yb = t * 32768;

      // hoist B(t) frags (wave-local LDS reads; data never overwritten)
      short8 bfh[2][4], bfl[2][4];   // [s][n2]
#pragma unroll
      for (int s = 0; s < 2; ++s)
#pragma unroll
        for (int q = 0; q < 4; ++q) {
          int rb = wc * 64 + q * 16 + lr;
          int ob = (s * 64 + hg * 16) ^ ((rb & 7) << 4);
          bfh[s][q] = *(const short8*)(lds + yb + rb * 128 + ob);
          bfl[s][q] = *(const short8*)(lds + yb + 16384 + rb * 128 + ob);
        }

      float4 cyv[4];
#pragma unroll
      for (int n2 = 0; n2 < 4; ++n2) {
        float4 yq = *(const float4*)&ysq[jt + wc * 64 + n2 * 16 + hg * 4];
        cyv[n2] = make_float4(cf * yq.x, cf * yq.y, cf * yq.z, cf * yq.w);
      }

      // 16 fenced sub-tiles: 6 MFMAs + 4 exp + 1 float4 store each
#pragma unroll
      for (int m2 = 0; m2 < 4; ++m2) {
        long row = i0 + wr * 64 + m2 * 16 + lr;
        float* op = Out + row * (long)mcols + jt + wc * 64 + hg * 4;
#pragma unroll
        for (int n2 = 0; n2 < 4; ++n2) {
          f32x4 a = (f32x4){0.f, 0.f, 0.f, 0.f};
#pragma unroll
          for (int s = 0; s < 2; ++s) {
            a = __builtin_amdgcn_mfma_f32_16x16x32_bf16(bfh[s][n2], afh[s][m2], a, 0, 0, 0);
            a = __builtin_amdgcn_mfma_f32_16x16x32_bf16(bfh[s][n2], afl[s][m2], a, 0, 0, 0);
            a = __builtin_amdgcn_mfma_f32_16x16x32_bf16(bfl[s][n2], afh[s][m2], a, 0, 0, 0);
          }
          float o[4];
          o[0] = EXP2(fminf(fmaf(nc2, a[0], cxr[m2] + cyv[n2].x), 0.f));
          o[1] = EXP2(fminf(fmaf(nc2, a[1], cxr[m2] + cyv[n2].y), 0.f));
          o[2] = EXP2(fminf(fmaf(nc2, a[2], cxr[m2] + cyv[n2].z), 0.f));
          o[3] = EXP2(fminf(fmaf(nc2, a[3], cxr[m2] + cyv[n2].w), 0.f));
          *(float4*)(op + n2 * 16) = *(float4*)o;
          __builtin_amdgcn_sched_barrier(0);   // pin store spacing
        }
      }
    }

    // ---- load A(p+1) frags (independent L2 loads; no barrier, no LDS)
    if (p + 1 < IPB) {
#pragma unroll
      for (int s = 0; s < 2; ++s)
#pragma unroll
        for (int q = 0; q < 4; ++q) {
          afh[s][q] = XHf[fidx(ip + 1, s, wr * 4 + q) + lane];
          afl[s][q] = XLf[fidx(ip + 1, s, wr * 4 + q) + lane];
        }
    }
  }
}

// ---------------- fallback (proven round-2 path) ---------------------------
__global__ __launch_bounds__(256)
void prep_sq(const float* __restrict__ X, const float* __restrict__ Y,
             float* __restrict__ xsq, float* __restrict__ ysq, int n) {
  int t = blockIdx.x * 256 + threadIdx.x;
  int row = t >> 4;
  int c = t & 15;
  const float* src;
  float* dst;
  if (row < n) { src = X + (long)row * DD; dst = xsq + row; }
  else         { src = Y + (long)(row - n) * DD; dst = ysq + (row - n); }
  float4 v = ((const float4*)src)[c];
  float s = v.x * v.x + v.y * v.y + v.z * v.z + v.w * v.w;
  s += __shfl_xor(s, 1);
  s += __shfl_xor(s, 2);
  s += __shfl_xor(s, 4);
  s += __shfl_xor(s, 8);
  if (c == 0) *dst = s;
}

__global__ __launch_bounds__(256, 2)
void rbf_mfma_fb(const float* __restrict__ X, const float* __restrict__ Y,
                 const float* __restrict__ gptr,
                 const float* __restrict__ xsq, const float* __restrict__ ysq,
                 float* __restrict__ Out, int mcols) {
  __shared__ unsigned short XH[128 * DD], XL[128 * DD];
  __shared__ unsigned short YH[128 * DD], YL[128 * DD];
  const int tid = threadIdx.x;
  const long i0 = (long)blockIdx.y * 128;
  const long j0 = (long)blockIdx.x * 128;
#pragma unroll
  for (int it = 0; it < 16; ++it) {
    int e = it * 256 + tid;
    int half = e >> 11;
    int idx = e & 2047;
    int row = idx >> 4;
    int c4 = idx & 15;
    const float* src = half ? (Y + (j0 + row) * DD) : (X + (i0 + row) * DD);
    float4 v = ((const float4*)src)[c4];
    float f[4] = {v.x, v.y, v.z, v.w};
    unsigned short h[4], l[4];
#pragma unroll
    for (int q = 0; q < 4; ++q) {
      h[q] = f2bf_rne(f[q]);
      float hv = __uint_as_float(((unsigned)h[q]) << 16);
      l[q] = f2bf_rne(f[q] - hv);
    }
    int sw = (c4 * 8) ^ ((row & 7) << 4);
    unsigned short* Ht = half ? YH : XH;
    unsigned short* Lt = half ? YL : XL;
    *(ushort4*)((char*)Ht + row * 128 + sw) = make_ushort4(h[0], h[1], h[2], h[3]);
    *(ushort4*)((char*)Lt + row * 128 + sw) = make_ushort4(l[0], l[1], l[2], l[3]);
  }
  __syncthreads();
  const int lane = tid & 63;
  const int wid = tid >> 6;
  const int wr = wid >> 1, wc = wid & 1;
  const int lr = lane & 15;
  const int hg = lane >> 4;
  f32x4 acc[4][4];
#pragma unroll
  for (int a = 0; a < 4; ++a)
#pragma unroll
    for (int c = 0; c < 4; ++c) acc[a][c] = (f32x4){0.f, 0.f, 0.f, 0.f};
  const unsigned short* At[3] = {XH, XL, XH};
  const unsigned short* Bt[3] = {YH, YH, YL};
#pragma unroll
  for (int p = 0; p < 3; ++p) {
#pragma unroll
    for (int s = 0; s < 2; ++s) {
      const int kbyte = s * 64 + hg * 16;
      short8 af[4], bfv[4];
#pragma unroll
      for (int m2 = 0; m2 < 4; ++m2) {
        int row = wr * 64 + m2 * 16 + lr;
        af[m2] = *(const short8*)((const char*)At[p] + row * 128 + (kbyte ^ ((row & 7) << 4)));
      }
#pragma unroll
      for (int n2 = 0; n2 < 4; ++n2) {
        int row = wc * 64 + n2 * 16 + lr;
        bfv[n2] = *(const short8*)((const char*)Bt[p] + row * 128 + (kbyte ^ ((row & 7) << 4)));
      }
#pragma unroll
      for (int m2 = 0; m2 < 4; ++m2)
#pragma unroll
        for (int n2 = 0; n2 < 4; ++n2)
          acc[m2][n2] = __builtin_amdgcn_mfma_f32_16x16x32_bf16(af[m2], bfv[n2], acc[m2][n2], 0, 0, 0);
    }
  }
  const float g = *gptr;
  float yv[4];
#pragma unroll
  for (int n2 = 0; n2 < 4; ++n2) yv[n2] = ysq[j0 + wc * 64 + n2 * 16 + lr];
#pragma unroll
  for (int m2 = 0; m2 < 4; ++m2) {
#pragma unroll
    for (int j = 0; j < 4; ++j) {
      long row = i0 + wr * 64 + m2 * 16 + hg * 4 + j;
      float xr = xsq[row];
      float* op = Out + row * (long)mcols + j0 + wc * 64 + lr;
#pragma unroll
      for (int n2 = 0; n2 < 4; ++n2) {
        float d = fmaxf(xr + yv[n2] - 2.0f * acc[m2][n2][j], 0.f);
        op[n2 * 16] = __expf(-g * d);
      }
    }
  }
}

extern "C" void kernel_launch(void* const* d_in, const int* in_sizes, int n_in,
                              void* d_out, int out_size, void* d_ws, size_t ws_size,
                              hipStream_t stream) {
  const float* x = (const float*)d_in[0];
  const float* y = (const float*)d_in[1];
  const float* g = (const float*)d_in[2];
  float* out = (float*)d_out;

  const int n = in_sizes[0] / DD;   // 8192
  const int m = in_sizes[1] / DD;   // 8192

  const size_t split_bytes = (size_t)(n + m) * DD * 2 * sizeof(unsigned short);
  const size_t needed = split_bytes + (size_t)(n + m) * sizeof(float);

  if (ws_size >= needed && (n % (BM * IPB)) == 0 && (m % (2 * BN)) == 0) {
    short8* XHf = (short8*)d_ws;                       // n*DD/8 short8
    short8* XLf = XHf + (size_t)n * DD / 8;
    unsigned short* YHg = (unsigned short*)(XLf + (size_t)n * DD / 8);
    unsigned short* YLg = YHg + (size_t)m * DD;
    float* xsq = (float*)(YLg + (size_t)m * DD);
    float* ysq = xsq + n;
    prep_mix2<<<(n + m) * 8 / 256, 256, 0, stream>>>(x, y, XHf, XLf, YHg, YLg, xsq, ysq, n);
    dim3 grid(m / (2 * BN), n / (BM * IPB));   // 32 x 16 = 512 blocks (2/CU)
    rbf_isweep<<<grid, 256, 0, stream>>>(XHf, XLf, YHg, YLg, g, xsq, ysq, out, m);
  } else {
    float* xsq = (float*)d_ws;
    float* ysq = xsq + n;
    prep_sq<<<(n + m) / 16, 256, 0, stream>>>(x, y, xsq, ysq, n);
    dim3 grid2(m / 128, n / 128);
    rbf_mfma_fb<<<grid2, 256, 0, stream>>>(x, y, g, xsq, ysq, out, m);
  }
}